// Round 9
// baseline (352.888 us; speedup 1.0000x reference)
//
#include <hip/hip_runtime.h>
#include <stdint.h>

#define S_ROWS 100000
#define NQ     2048
#define M_POS  16
#define VOCABS 32
#define GROUPS 2      // query groups of 1024
#define CHUNKS 250
#define RC     400    // rows per chunk
#define SUBS   8      // rows in flight per block iteration
#define NPAIR  25     // RC / SUBS / 2 (pair loop)
#define KPAD   264

// ---------------- kernel 1: decode one-hot support rows to token bytes (v*8) ----
// Also zero-inits best[] (workspace is re-poisoned each iteration).
__global__ __launch_bounds__(256) void knn_decode(const float* __restrict__ support,
                                                  uint8_t* __restrict__ tok,
                                                  uint32_t* __restrict__ best) {
    if (blockIdx.x < 8) best[blockIdx.x * 256 + threadIdx.x] = 0u;
    int wave = (blockIdx.x * 256 + threadIdx.x) >> 6;   // one wave per row
    int lane = threadIdx.x & 63;
    if (wave >= S_ROWS) return;
    const float4* rowp = (const float4*)(support + (size_t)wave * 512) + lane * 2;
    float4 f0 = rowp[0];
    float4 f1 = rowp[1];
    float base = (float)((lane & 3) * 64);
    float v = f0.x * (base + 0.f)  + f0.y * (base + 8.f)  + f0.z * (base + 16.f) + f0.w * (base + 24.f)
            + f1.x * (base + 32.f) + f1.y * (base + 40.f) + f1.z * (base + 48.f) + f1.w * (base + 56.f);
    v += __shfl_xor(v, 1);
    v += __shfl_xor(v, 2);
    if ((lane & 3) == 0) {
        int p = lane >> 2;
        tok[(size_t)wave * 16 + p] = (uint8_t)(v + 0.5f);   // v*8, <=248
    }
}

// full adder / half adder on bit-planes
__device__ __forceinline__ void FA(uint32_t a, uint32_t b, uint32_t c,
                                   uint32_t& s, uint32_t& co) {
    uint32_t x = a ^ b;
    s  = x ^ c;
    co = (a & b) | (x & c);
}
__device__ __forceinline__ void HA(uint32_t a, uint32_t b, uint32_t& s, uint32_t& co) {
    s = a ^ b; co = a & b;
}

// gather 16 table words; table byte addr = m*4096 + e*16 + w*4 (e = v*8).
// For each sub, lanes w=0..31 read 32 consecutive words -> all 32 banks exactly
// once; 2 subs per wave -> exactly 2 lanes/bank: conflict-free by construction.
__device__ __forceinline__ void gather16(const char* __restrict__ tb, uint4 ta,
                                         uint32_t b[16]) {
    b[0]  = *(const uint32_t*)(tb + ( ta.x        & 0xFFu) * 16 +  0*4096);
    b[1]  = *(const uint32_t*)(tb + ((ta.x >> 8)  & 0xFFu) * 16 +  1*4096);
    b[2]  = *(const uint32_t*)(tb + ((ta.x >> 16) & 0xFFu) * 16 +  2*4096);
    b[3]  = *(const uint32_t*)(tb + ((ta.x >> 24)        ) * 16 +  3*4096);
    b[4]  = *(const uint32_t*)(tb + ( ta.y        & 0xFFu) * 16 +  4*4096);
    b[5]  = *(const uint32_t*)(tb + ((ta.y >> 8)  & 0xFFu) * 16 +  5*4096);
    b[6]  = *(const uint32_t*)(tb + ((ta.y >> 16) & 0xFFu) * 16 +  6*4096);
    b[7]  = *(const uint32_t*)(tb + ((ta.y >> 24)        ) * 16 +  7*4096);
    b[8]  = *(const uint32_t*)(tb + ( ta.z        & 0xFFu) * 16 +  8*4096);
    b[9]  = *(const uint32_t*)(tb + ((ta.z >> 8)  & 0xFFu) * 16 +  9*4096);
    b[10] = *(const uint32_t*)(tb + ((ta.z >> 16) & 0xFFu) * 16 + 10*4096);
    b[11] = *(const uint32_t*)(tb + ((ta.z >> 24)        ) * 16 + 11*4096);
    b[12] = *(const uint32_t*)(tb + ( ta.w        & 0xFFu) * 16 + 12*4096);
    b[13] = *(const uint32_t*)(tb + ((ta.w >> 8)  & 0xFFu) * 16 + 13*4096);
    b[14] = *(const uint32_t*)(tb + ((ta.w >> 16) & 0xFFu) * 16 + 14*4096);
    b[15] = *(const uint32_t*)(tb + ((ta.w >> 24)        ) * 16 + 15*4096);
}

// CSA popcount + bit-sliced max/argmax update; k (0..49) via SALU masks, 6 planes.
__device__ __forceinline__ void score_row(const uint32_t b[16], int k,
        uint32_t& cp0, uint32_t& cp1, uint32_t& cp2, uint32_t& cp3, uint32_t& cp4,
        uint32_t& k0p, uint32_t& k1p, uint32_t& k2p, uint32_t& k3p, uint32_t& k4p,
        uint32_t& k5p) {
    uint32_t s10,s11,s12,s13,s14, c10,c11,c12,c13,c14;
    FA(b[0],b[1],b[2],   s10,c10);
    FA(b[3],b[4],b[5],   s11,c11);
    FA(b[6],b[7],b[8],   s12,c12);
    FA(b[9],b[10],b[11], s13,c13);
    FA(b[12],b[13],b[14],s14,c14);
    uint32_t s2a,c2a,s2b,c2b;
    FA(s10,s11,s12, s2a,c2a);
    FA(s13,s14,b[15], s2b,c2b);
    uint32_t n0,h0;  HA(s2a,s2b, n0,h0);
    uint32_t u,cu,vv,cv,x2,cx,n1,cy;
    FA(c10,c11,c12, u,cu);
    FA(c13,c14,c2a, vv,cv);
    FA(u,vv,c2b,    x2,cx);
    HA(x2,h0,       n1,cy);
    uint32_t y4,cz,n2,cw,n3,n4;
    FA(cu,cv,cx, y4,cz);
    HA(y4,cy,    n2,cw);
    HA(cz,cw,    n3,n4);

    uint32_t eq = ~(n4 ^ cp4);
    uint32_t gt = n4 & ~cp4;
    gt |= eq & (n3 & ~cp3);  eq &= ~(n3 ^ cp3);
    gt |= eq & (n2 & ~cp2);  eq &= ~(n2 ^ cp2);
    gt |= eq & (n1 & ~cp1);  eq &= ~(n1 ^ cp1);
    gt |= eq & (n0 & ~cp0);

    uint32_t ng = ~gt;
    cp0 = (gt & n0) | (ng & cp0);
    cp1 = (gt & n1) | (ng & cp1);
    cp2 = (gt & n2) | (ng & cp2);
    cp3 = (gt & n3) | (ng & cp3);
    cp4 = (gt & n4) | (ng & cp4);
    uint32_t kb0 = 0u - (uint32_t)( k       & 1);
    uint32_t kb1 = 0u - (uint32_t)((k >> 1) & 1);
    uint32_t kb2 = 0u - (uint32_t)((k >> 2) & 1);
    uint32_t kb3 = 0u - (uint32_t)((k >> 3) & 1);
    uint32_t kb4 = 0u - (uint32_t)((k >> 4) & 1);
    uint32_t kb5 = 0u - (uint32_t)((k >> 5) & 1);
    k0p = (k0p & ng) | (gt & kb0);
    k1p = (k1p & ng) | (gt & kb1);
    k2p = (k2p & ng) | (gt & kb2);
    k3p = (k3p & ng) | (gt & kb3);
    k4p = (k4p & ng) | (gt & kb4);
    k5p = (k5p & ng) | (gt & kb5);
}

// ---------------- kernel 2: bit-sliced match-count + argmax --------------------
// New geometry: 1024-query blocks (GROUPS=2), table[m][v][wb] = 16x32x32 words
// (64 KB LDS, 2 blocks/CU). Wave = 2 subs x 32 words -> gathers are 32
// consecutive words per sub = exactly 2 lanes/bank: ZERO bank conflicts (the
// old 8-sub x 8-word geometry had a data-dependent ~1.7x conflict tax that no
// swizzle could remove, since each sub always covered a full 8-bank row).
__global__ __launch_bounds__(256)
__attribute__((amdgpu_waves_per_eu(2, 2)))
void knn_score(const int* __restrict__ utts,
               const uint8_t* __restrict__ tok,
               uint32_t* __restrict__ best) {
    __shared__ uint32_t smem[16384];   // 64 KB: table in main loop, keys after

    const int bid = blockIdx.x;
    const int g   = bid & 1;          // query group (1024 queries)
    const int c   = bid >> 1;         // row chunk (0..249)
    const int t   = threadIdx.x;

    // zero table
    #pragma unroll
    for (int i = 0; i < 64; ++i) smem[t + 256 * i] = 0u;
    __syncthreads();

    // build: thread t loads 4 consecutive queries (coalesced int4), wb = t>>3
    // table[m*1024 + v*32 + wb] bit j = (utts[m][g*1024 + wb*32 + j] == v)
    {
        int wb = t >> 3;                       // = (4t+ii)>>5, constant per thread
        int jb = (t & 7) * 4;                  // j = jb + ii
        #pragma unroll
        for (int m = 0; m < M_POS; ++m) {
            int4 q4 = *((const int4*)(utts + m * NQ + g * 1024) + t);
            atomicOr(&smem[m * 1024 + q4.x * 32 + wb], 1u << (jb + 0));
            atomicOr(&smem[m * 1024 + q4.y * 32 + wb], 1u << (jb + 1));
            atomicOr(&smem[m * 1024 + q4.z * 32 + wb], 1u << (jb + 2));
            atomicOr(&smem[m * 1024 + q4.w * 32 + wb], 1u << (jb + 3));
        }
    }
    __syncthreads();

    const int w   = t & 31;           // word this thread scores (32 queries)
    const int sub = t >> 5;           // row sub-lane (0..7)
    const int r0  = c * RC;
    const char* tb = (const char*)smem + w * 4;

    uint32_t cp0=0,cp1=0,cp2=0,cp3=0,cp4=0;         // current-max count planes
    uint32_t k0p=0,k1p=0,k2p=0,k3p=0,k4p=0,k5p=0;   // winning-iteration planes

    const uint4* tbase = (const uint4*)tok + (r0 + sub);   // row stride 8 per iter

    // pair loop: rows r0 + sub + 8*(2j) and +8*(2j+1); 25 pairs = 50 rows
    uint4 tA = tbase[0];
    uint4 tB = tbase[8];
    #pragma unroll 1
    for (int j = 0; j < NPAIR; ++j) {
        uint4 tAn, tBn;
        if (j + 1 < NPAIR) {
            tAn = tbase[8 * (2 * j + 2)];
            tBn = tbase[8 * (2 * j + 3)];
        } else {
            tAn = tA; tBn = tB;
        }
        uint32_t b0[16], b1[16];
        gather16(tb, tA, b0);              // 32 conflict-free ds_reads in flight
        gather16(tb, tB, b1);
        score_row(b0, 2 * j,     cp0,cp1,cp2,cp3,cp4, k0p,k1p,k2p,k3p,k4p,k5p);
        score_row(b1, 2 * j + 1, cp0,cp1,cp2,cp3,cp4, k0p,k1p,k2p,k3p,k4p,k5p);
        tA = tAn; tB = tBn;
    }

    __syncthreads();   // all table gathers done before keys overwrite smem

    // extract per-query packed keys: key = (cnt<<17) | (0x1FFFF - idx),
    // idx = r0 + sub + 8*kk
    {
        uint32_t C = 0x1FFFFu - (uint32_t)(r0 + sub);
        #pragma unroll
        for (int j = 0; j < 32; ++j) {
            uint32_t cnt = ((cp0>>j)&1u) | (((cp1>>j)&1u)<<1) | (((cp2>>j)&1u)<<2)
                         | (((cp3>>j)&1u)<<3) | (((cp4>>j)&1u)<<4);
            uint32_t kk  = ((k0p>>j)&1u) | (((k1p>>j)&1u)<<1) | (((k2p>>j)&1u)<<2)
                         | (((k3p>>j)&1u)<<3) | (((k4p>>j)&1u)<<4) | (((k5p>>j)&1u)<<5);
            uint32_t key = (cnt << 17) + C - (kk << 3);
            smem[j * KPAD + t] = key;          // bank = t&31: conflict-free
        }
    }
    __syncthreads();

    // reduce over 8 subs; thread t owns (w2 = t&31, j2 = t>>5), 4 j's each
    {
        int w2 = t & 31, j2 = t >> 5;
        #pragma unroll
        for (int jj = 0; jj < 4; ++jj) {
            int j = j2 + 8 * jj;
            uint32_t bestv = 0;
            #pragma unroll
            for (int s = 0; s < 8; ++s) {
                uint32_t v = smem[j * KPAD + s * 32 + w2];
                bestv = bestv > v ? bestv : v;
            }
            atomicMax(&best[g * 1024 + w2 * 32 + j], bestv);
        }
    }
}

// ---------------- kernel 3: one-hot output from best[] -------------------------
__global__ __launch_bounds__(256) void knn_out(const uint32_t* __restrict__ best,
                                               const int* __restrict__ meanings,
                                               float* __restrict__ out) {
    int q = blockIdx.x * 256 + threadIdx.x;
    if (q >= NQ) return;
    uint32_t b = best[q];
    int idx = 0x1FFFF - (int)(b & 0x1FFFFu);
    float* o = out + (size_t)q * 50;
    #pragma unroll
    for (int tt = 0; tt < 5; ++tt) {
        int mv = meanings[(size_t)idx * 5 + tt];
        #pragma unroll
        for (int mm = 0; mm < 10; ++mm) o[tt * 10 + mm] = (mm == mv) ? 1.0f : 0.0f;
    }
}

extern "C" void kernel_launch(void* const* d_in, const int* in_sizes, int n_in,
                              void* d_out, int out_size, void* d_ws, size_t ws_size,
                              hipStream_t stream) {
    const int*   utts     = (const int*)d_in[0];     // [16, 2048]
    const float* support  = (const float*)d_in[1];   // [100000, 512]
    const int*   meanings = (const int*)d_in[2];     // [100000, 5]
    float* out = (float*)d_out;                      // [2048, 5, 10]

    uint8_t*  tok  = (uint8_t*)d_ws;                                   // 1.6 MB
    uint32_t* best = (uint32_t*)((char*)d_ws + (size_t)S_ROWS * 16);   // 8 KB

    knn_decode<<<(S_ROWS + 3) / 4, 256, 0, stream>>>(support, tok, best);
    knn_score<<<GROUPS * CHUNKS, 256, 0, stream>>>(utts, tok, best);
    knn_out<<<NQ / 256, 256, 0, stream>>>(best, meanings, out);
}

// Round 10
// 342.314 us; speedup vs baseline: 1.0309x; 1.0309x over previous
//
#include <hip/hip_runtime.h>
#include <stdint.h>

#define S_ROWS 100000
#define NQ     2048
#define M_POS  16
#define VOCABS 32
#define WPB    8      // 32-query words per score block (256 queries)
#define GROUPS 8      // 2048 / 256
#define CHUNKS 625
#define RC     160    // rows per chunk (32 * 5)
#define KITER  5      // RC / 32
#define KPAD   264    // padded stride for keys transpose

// ---------------- kernel 1: decode one-hot support rows to token bytes (v*8) ----
// Also zero-inits best[] (workspace is re-poisoned each iteration).
__global__ __launch_bounds__(256) void knn_decode(const float* __restrict__ support,
                                                  uint8_t* __restrict__ tok,
                                                  uint32_t* __restrict__ best) {
    if (blockIdx.x < 8) best[blockIdx.x * 256 + threadIdx.x] = 0u;
    int wave = (blockIdx.x * 256 + threadIdx.x) >> 6;   // one wave per row
    int lane = threadIdx.x & 63;
    if (wave >= S_ROWS) return;
    const float4* rowp = (const float4*)(support + (size_t)wave * 512) + lane * 2;
    float4 f0 = rowp[0];
    float4 f1 = rowp[1];
    float base = (float)((lane & 3) * 64);
    float v = f0.x * (base + 0.f)  + f0.y * (base + 8.f)  + f0.z * (base + 16.f) + f0.w * (base + 24.f)
            + f1.x * (base + 32.f) + f1.y * (base + 40.f) + f1.z * (base + 48.f) + f1.w * (base + 56.f);
    v += __shfl_xor(v, 1);
    v += __shfl_xor(v, 2);
    if ((lane & 3) == 0) {
        int p = lane >> 2;
        tok[(size_t)wave * 16 + p] = (uint8_t)(v + 0.5f);   // v*8, <=248
    }
}

// full adder / half adder on bit-planes
__device__ __forceinline__ void FA(uint32_t a, uint32_t b, uint32_t c,
                                   uint32_t& s, uint32_t& co) {
    uint32_t x = a ^ b;
    s  = x ^ c;
    co = (a & b) | (x & c);
}
__device__ __forceinline__ void HA(uint32_t a, uint32_t b, uint32_t& s, uint32_t& co) {
    s = a ^ b; co = a & b;
}

__device__ __forceinline__ void gather16(const uint32_t* __restrict__ tw, uint4 ta,
                                         uint32_t b[16]) {
    b[0]  = tw[ (ta.x        & 0xFFu) +  0*256];
    b[1]  = tw[((ta.x >> 8)  & 0xFFu) +  1*256];
    b[2]  = tw[((ta.x >> 16) & 0xFFu) +  2*256];
    b[3]  = tw[((ta.x >> 24)        ) +  3*256];
    b[4]  = tw[ (ta.y        & 0xFFu) +  4*256];
    b[5]  = tw[((ta.y >> 8)  & 0xFFu) +  5*256];
    b[6]  = tw[((ta.y >> 16) & 0xFFu) +  6*256];
    b[7]  = tw[((ta.y >> 24)        ) +  7*256];
    b[8]  = tw[ (ta.z        & 0xFFu) +  8*256];
    b[9]  = tw[((ta.z >> 8)  & 0xFFu) +  9*256];
    b[10] = tw[((ta.z >> 16) & 0xFFu) + 10*256];
    b[11] = tw[((ta.z >> 24)        ) + 11*256];
    b[12] = tw[ (ta.w        & 0xFFu) + 12*256];
    b[13] = tw[((ta.w >> 8)  & 0xFFu) + 13*256];
    b[14] = tw[((ta.w >> 16) & 0xFFu) + 14*256];
    b[15] = tw[((ta.w >> 24)        ) + 15*256];
}

// CSA popcount + bit-sliced max/argmax update; k (0..4) via SALU masks, 3 planes.
__device__ __forceinline__ void score_row(const uint32_t b[16], int k,
        uint32_t& cp0, uint32_t& cp1, uint32_t& cp2, uint32_t& cp3, uint32_t& cp4,
        uint32_t& k0p, uint32_t& k1p, uint32_t& k2p) {
    uint32_t s10,s11,s12,s13,s14, c10,c11,c12,c13,c14;
    FA(b[0],b[1],b[2],   s10,c10);
    FA(b[3],b[4],b[5],   s11,c11);
    FA(b[6],b[7],b[8],   s12,c12);
    FA(b[9],b[10],b[11], s13,c13);
    FA(b[12],b[13],b[14],s14,c14);
    uint32_t s2a,c2a,s2b,c2b;
    FA(s10,s11,s12, s2a,c2a);
    FA(s13,s14,b[15], s2b,c2b);
    uint32_t n0,h0;  HA(s2a,s2b, n0,h0);
    uint32_t u,cu,vv,cv,x2,cx,n1,cy;
    FA(c10,c11,c12, u,cu);
    FA(c13,c14,c2a, vv,cv);
    FA(u,vv,c2b,    x2,cx);
    HA(x2,h0,       n1,cy);
    uint32_t y4,cz,n2,cw,n3,n4;
    FA(cu,cv,cx, y4,cz);
    HA(y4,cy,    n2,cw);
    HA(cz,cw,    n3,n4);

    uint32_t eq = ~(n4 ^ cp4);
    uint32_t gt = n4 & ~cp4;
    gt |= eq & (n3 & ~cp3);  eq &= ~(n3 ^ cp3);
    gt |= eq & (n2 & ~cp2);  eq &= ~(n2 ^ cp2);
    gt |= eq & (n1 & ~cp1);  eq &= ~(n1 ^ cp1);
    gt |= eq & (n0 & ~cp0);

    uint32_t ng = ~gt;
    cp0 = (gt & n0) | (ng & cp0);
    cp1 = (gt & n1) | (ng & cp1);
    cp2 = (gt & n2) | (ng & cp2);
    cp3 = (gt & n3) | (ng & cp3);
    cp4 = (gt & n4) | (ng & cp4);
    uint32_t kb0 = 0u - (uint32_t)( k       & 1);
    uint32_t kb1 = 0u - (uint32_t)((k >> 1) & 1);
    uint32_t kb2 = 0u - (uint32_t)((k >> 2) & 1);
    k0p = (k0p & ng) | (gt & kb0);
    k1p = (k1p & ng) | (gt & kb1);
    k2p = (k2p & ng) | (gt & kb2);
}

// ---------------- kernel 2: bit-sliced match-count + argmax --------------------
// R8 geometry (8 words x 32 subs, 16 KB table, ~1.7x conflicts tolerated) at
// 2x the TLP: RC=160 -> 5000 blocks; LDS shrunk to 16.9 KB via 2-pass key
// extract -> 8 blocks/CU (32-wave cap) instead of 4. R8->R9 showed score time
// scales ~1/waves (stall-bound), so conflicts don't matter but waves do.
// waves_per_eu(4,8): 128-reg hard budget (no spill) with 8/EU aspiration
// (live set ~58 regs should fit 64 -> 8 waves/EU).
__global__ __launch_bounds__(256)
__attribute__((amdgpu_waves_per_eu(4, 8)))
void knn_score(const int* __restrict__ utts,
               const uint8_t* __restrict__ tok,
               uint32_t* __restrict__ best) {
    __shared__ uint32_t smem[16 * KPAD];    // 4224 words = 16.9 KB (>= 4096 table)
    uint32_t* table = smem;                 // 4096 words during main loop
    uint32_t* keys  = smem;                 // 16 x KPAD after main loop

    const int bid = blockIdx.x;
    const int g   = bid & 7;          // query group (256 queries)
    const int c   = bid >> 3;         // row chunk (0..624)
    const int t   = threadIdx.x;

    // zero table
    #pragma unroll
    for (int i = 0; i < 16; ++i) table[t + 256 * i] = 0u;
    __syncthreads();

    // build query-bitmask table: B[m][v][w] bit j = (utts[m][g*256+w*32+j] == v)
    {
        int q = g * 256 + t;
        int wb = t >> 5, j = t & 31;
        #pragma unroll
        for (int m = 0; m < M_POS; ++m) {
            int v = utts[m * NQ + q];
            atomicOr(&table[(m * VOCABS + v) * WPB + wb], 1u << j);
        }
    }
    __syncthreads();

    const int w   = t & 7;            // which 32-query word this thread scores
    const int sub = t >> 3;           // row sub-lane (0..31)
    const int r0  = c * RC;
    const uint32_t* tw = table + w;

    uint32_t cp0=0,cp1=0,cp2=0,cp3=0,cp4=0;   // current-max count planes
    uint32_t k0p=0,k1p=0,k2p=0;               // winning-iteration planes (0..4)

    const uint4* tbase = (const uint4*)(tok + (size_t)(r0 + sub) * 16);

    uint4 tA = tbase[0];
    #pragma unroll 1
    for (int k = 0; k < KITER; ++k) {
        int kn = (k + 1 < KITER) ? k + 1 : k;
        uint4 tAn = tbase[32 * kn];            // prefetch next row's tokens
        uint32_t b[16];
        gather16(tw, tA, b);
        score_row(b, k, cp0,cp1,cp2,cp3,cp4, k0p,k1p,k2p);
        tA = tAn;
    }

    __syncthreads();   // all table gathers done before keys overwrite the union

    // 2-pass extract + reduce (keys buffer = 16 rows -> LDS stays 16.9 KB)
    // key = (cnt << 17) | (0x1FFFF - idx); idx = r0 + sub + 32*kk
    uint32_t C = 0x1FFFFu - (uint32_t)(r0 + sub);
    #pragma unroll
    for (int P = 0; P < 2; ++P) {
        #pragma unroll
        for (int jj = 0; jj < 16; ++jj) {
            int j = P * 16 + jj;
            uint32_t cnt = ((cp0>>j)&1u) | (((cp1>>j)&1u)<<1) | (((cp2>>j)&1u)<<2)
                         | (((cp3>>j)&1u)<<3) | (((cp4>>j)&1u)<<4);
            uint32_t kk  = ((k0p>>j)&1u) | (((k1p>>j)&1u)<<1) | (((k2p>>j)&1u)<<2);
            uint32_t key = (cnt << 17) + C - (kk << 5);
            keys[jj * KPAD + t] = key;         // bank = t&31: conflict-free
        }
        __syncthreads();
        // reduce: thread t owns (w2 = t&7, jr = (t>>3)&15, half sh = t>>7);
        // max over 16 subs, then atomicMax (2 per query per block).
        {
            int w2 = t & 7, jr = (t >> 3) & 15, sh = t >> 7;
            const uint32_t* kp = keys + jr * KPAD + sh * 128 + w2;
            uint32_t bv = 0;
            #pragma unroll
            for (int i = 0; i < 16; ++i) {
                uint32_t v = kp[8 * i];
                bv = bv > v ? bv : v;
            }
            atomicMax(&best[g * 256 + w2 * 32 + P * 16 + jr], bv);
        }
        __syncthreads();   // before pass B overwrites keys
    }
}

// ---------------- kernel 3: one-hot output from best[] -------------------------
__global__ __launch_bounds__(256) void knn_out(const uint32_t* __restrict__ best,
                                               const int* __restrict__ meanings,
                                               float* __restrict__ out) {
    int q = blockIdx.x * 256 + threadIdx.x;
    if (q >= NQ) return;
    uint32_t b = best[q];
    int idx = 0x1FFFF - (int)(b & 0x1FFFFu);
    float* o = out + (size_t)q * 50;
    #pragma unroll
    for (int tt = 0; tt < 5; ++tt) {
        int mv = meanings[(size_t)idx * 5 + tt];
        #pragma unroll
        for (int mm = 0; mm < 10; ++mm) o[tt * 10 + mm] = (mm == mv) ? 1.0f : 0.0f;
    }
}

extern "C" void kernel_launch(void* const* d_in, const int* in_sizes, int n_in,
                              void* d_out, int out_size, void* d_ws, size_t ws_size,
                              hipStream_t stream) {
    const int*   utts     = (const int*)d_in[0];     // [16, 2048]
    const float* support  = (const float*)d_in[1];   // [100000, 512]
    const int*   meanings = (const int*)d_in[2];     // [100000, 5]
    float* out = (float*)d_out;                      // [2048, 5, 10]

    uint8_t*  tok  = (uint8_t*)d_ws;                                   // 1.6 MB
    uint32_t* best = (uint32_t*)((char*)d_ws + (size_t)S_ROWS * 16);   // 8 KB

    knn_decode<<<(S_ROWS + 3) / 4, 256, 0, stream>>>(support, tok, best);
    knn_score<<<GROUPS * CHUNKS, 256, 0, stream>>>(utts, tok, best);
    knn_out<<<NQ / 256, 256, 0, stream>>>(best, meanings, out);
}

// Round 11
// 313.584 us; speedup vs baseline: 1.1253x; 1.0916x over previous
//
#include <hip/hip_runtime.h>
#include <stdint.h>

#define S_ROWS 100000
#define NQ     2048
#define M_POS  16
#define VOCABS 32
#define WPB    8      // 32-query words per score block (256 queries)
#define GROUPS 8      // 2048 / 256
#define CHUNKS 125
#define RC     800    // rows per chunk
#define KITER  25     // RC / 32
#define KPAD   264    // padded stride for keys transpose (conflict-free)

// ---------------- kernel 1: decode one-hot support rows to token bytes (v*8) ----
// Also zero-inits best[] (workspace is re-poisoned each iteration, and poison
// garbage would beat any real key in the atomicMax).
__global__ __launch_bounds__(256) void knn_decode(const float* __restrict__ support,
                                                  uint8_t* __restrict__ tok,
                                                  uint32_t* __restrict__ best) {
    if (blockIdx.x < 8) best[blockIdx.x * 256 + threadIdx.x] = 0u;
    int wave = (blockIdx.x * 256 + threadIdx.x) >> 6;   // one wave per row
    int lane = threadIdx.x & 63;
    if (wave >= S_ROWS) return;
    const float4* rowp = (const float4*)(support + (size_t)wave * 512) + lane * 2;
    float4 f0 = rowp[0];
    float4 f1 = rowp[1];
    // token index within position = (lane&3)*8 + i ; store pre-scaled by 8 (fits u8: <=248)
    float base = (float)((lane & 3) * 64);
    float v = f0.x * (base + 0.f)  + f0.y * (base + 8.f)  + f0.z * (base + 16.f) + f0.w * (base + 24.f)
            + f1.x * (base + 32.f) + f1.y * (base + 40.f) + f1.z * (base + 48.f) + f1.w * (base + 56.f);
    v += __shfl_xor(v, 1);
    v += __shfl_xor(v, 2);
    if ((lane & 3) == 0) {
        int p = lane >> 2;
        tok[(size_t)wave * 16 + p] = (uint8_t)(v + 0.5f);
    }
}

// full adder / half adder on bit-planes
__device__ __forceinline__ void FA(uint32_t a, uint32_t b, uint32_t c,
                                   uint32_t& s, uint32_t& co) {
    uint32_t x = a ^ b;
    s  = x ^ c;
    co = (a & b) | (x & c);
}
__device__ __forceinline__ void HA(uint32_t a, uint32_t b, uint32_t& s, uint32_t& co) {
    s = a ^ b; co = a & b;
}

// ---------------- kernel 2: bit-sliced match-count + argmax --------------------
// LDS: table (16 KB, live during main loop) aliased with keys transpose buffer
// (33.8 KB, live after) -> 34 KB total -> 4 blocks/CU.
__global__ __launch_bounds__(256, 4) void knn_score(const int* __restrict__ utts,
                                                    const uint8_t* __restrict__ tok,
                                                    uint32_t* __restrict__ best) {
    __shared__ uint32_t smem[32 * KPAD];               // 33.8 KB
    uint32_t* table = smem;                            // first 4096 words during main loop
    uint32_t* keys  = smem;                            // whole buffer, after main loop

    const int bid = blockIdx.x;
    const int g   = bid & 7;          // query group (256 queries)
    const int c   = bid >> 3;         // row chunk
    const int t   = threadIdx.x;

    // zero table
    #pragma unroll
    for (int i = 0; i < 16; ++i) table[t + 256 * i] = 0u;
    __syncthreads();

    // build query-bitmask table: B[m][v][w] bit j = (utts[m][g*256+w*32+j] == v)
    {
        int q = g * 256 + t;
        int wb = t >> 5, j = t & 31;
        #pragma unroll
        for (int m = 0; m < M_POS; ++m) {
            int v = utts[m * NQ + q];
            atomicOr(&table[(m * VOCABS + v) * WPB + wb], 1u << j);
        }
    }
    __syncthreads();

    const int w   = t & 7;            // which 32-query word this thread scores
    const int sub = t >> 3;           // row sub-lane (0..31)
    const int r0  = c * RC;
    const uint32_t* tw = table + w;

    uint32_t cp0=0,cp1=0,cp2=0,cp3=0,cp4=0;   // current-max count planes
    uint32_t k0p=0,k1p=0,k2p=0,k3p=0,k4p=0;   // winning-iteration planes

    const uint4* tbase = (const uint4*)(tok + (size_t)(r0 + sub) * 16);

    #pragma unroll 5
    for (int k = 0; k < KITER; ++k) {
        uint4 ta = tbase[32 * k];             // row s = r0 + sub + 32*k
        uint32_t b[16];
        b[0]  = tw[ (ta.x        & 0xFFu) +  0*256];
        b[1]  = tw[((ta.x >> 8)  & 0xFFu) +  1*256];
        b[2]  = tw[((ta.x >> 16) & 0xFFu) +  2*256];
        b[3]  = tw[((ta.x >> 24)        ) +  3*256];
        b[4]  = tw[ (ta.y        & 0xFFu) +  4*256];
        b[5]  = tw[((ta.y >> 8)  & 0xFFu) +  5*256];
        b[6]  = tw[((ta.y >> 16) & 0xFFu) +  6*256];
        b[7]  = tw[((ta.y >> 24)        ) +  7*256];
        b[8]  = tw[ (ta.z        & 0xFFu) +  8*256];
        b[9]  = tw[((ta.z >> 8)  & 0xFFu) +  9*256];
        b[10] = tw[((ta.z >> 16) & 0xFFu) + 10*256];
        b[11] = tw[((ta.z >> 24)        ) + 11*256];
        b[12] = tw[ (ta.w        & 0xFFu) + 12*256];
        b[13] = tw[((ta.w >> 8)  & 0xFFu) + 13*256];
        b[14] = tw[((ta.w >> 16) & 0xFFu) + 14*256];
        b[15] = tw[((ta.w >> 24)        ) + 15*256];

        // CSA tree: 16 one-bit planes -> 5-bit count planes n0..n4
        uint32_t s10,s11,s12,s13,s14, c10,c11,c12,c13,c14;
        FA(b[0],b[1],b[2],   s10,c10);
        FA(b[3],b[4],b[5],   s11,c11);
        FA(b[6],b[7],b[8],   s12,c12);
        FA(b[9],b[10],b[11], s13,c13);
        FA(b[12],b[13],b[14],s14,c14);
        uint32_t s2a,c2a,s2b,c2b;
        FA(s10,s11,s12, s2a,c2a);
        FA(s13,s14,b[15], s2b,c2b);
        uint32_t n0,h0;  HA(s2a,s2b, n0,h0);
        uint32_t u,cu,vv,cv,x2,cx,n1,cy;
        FA(c10,c11,c12, u,cu);
        FA(c13,c14,c2a, vv,cv);
        FA(u,vv,c2b,    x2,cx);
        HA(x2,h0,       n1,cy);
        uint32_t y4,cz,n2,cw,n3,n4;
        FA(cu,cv,cx, y4,cz);
        HA(y4,cy,    n2,cw);
        HA(cz,cw,    n3,n4);

        // gt = (new count > current max), 5-bit unsigned, bit-sliced
        uint32_t eq = ~(n4 ^ cp4);
        uint32_t gt = n4 & ~cp4;
        gt |= eq & (n3 & ~cp3);  eq &= ~(n3 ^ cp3);
        gt |= eq & (n2 & ~cp2);  eq &= ~(n2 ^ cp2);
        gt |= eq & (n1 & ~cp1);  eq &= ~(n1 ^ cp1);
        gt |= eq & (n0 & ~cp0);

        uint32_t ng = ~gt;
        cp0 = (gt & n0) | (ng & cp0);
        cp1 = (gt & n1) | (ng & cp1);
        cp2 = (gt & n2) | (ng & cp2);
        cp3 = (gt & n3) | (ng & cp3);
        cp4 = (gt & n4) | (ng & cp4);
        // wave-uniform masks of k's bits: SALU-computed, SGPR operand in the
        // VALU and/or below -> same cost as the literal-k version.
        uint32_t kb0 = 0u - (uint32_t)( k        & 1);
        uint32_t kb1 = 0u - (uint32_t)((k >> 1)  & 1);
        uint32_t kb2 = 0u - (uint32_t)((k >> 2)  & 1);
        uint32_t kb3 = 0u - (uint32_t)((k >> 3)  & 1);
        uint32_t kb4 = 0u - (uint32_t)((k >> 4)  & 1);
        k0p = (k0p & ng) | (gt & kb0);
        k1p = (k1p & ng) | (gt & kb1);
        k2p = (k2p & ng) | (gt & kb2);
        k3p = (k3p & ng) | (gt & kb3);
        k4p = (k4p & ng) | (gt & kb4);
    }

    __syncthreads();   // all table gathers done before keys overwrite the union

    // extract per-query packed keys into LDS (conflict-free layout, no atomics)
    // key = (cnt << 17) | (0x1FFFF - idx); idx = r0 + sub + 32*kk
    {
        uint32_t C = 0x1FFFFu - (uint32_t)(r0 + sub);
        #pragma unroll
        for (int j = 0; j < 32; ++j) {
            uint32_t cnt = ((cp0>>j)&1u) | (((cp1>>j)&1u)<<1) | (((cp2>>j)&1u)<<2)
                         | (((cp3>>j)&1u)<<3) | (((cp4>>j)&1u)<<4);
            uint32_t kk  = ((k0p>>j)&1u) | (((k1p>>j)&1u)<<1) | (((k2p>>j)&1u)<<2)
                         | (((k3p>>j)&1u)<<3) | (((k4p>>j)&1u)<<4);
            uint32_t key = (cnt << 17) + C - (kk << 5);
            keys[j * KPAD + t] = key;           // bank = t&31: conflict-free
        }
    }
    __syncthreads();

    // reduce: thread t owns query (w2 = t&7, j2 = t>>3); max over 32 sub-threads,
    // then one device-scope atomicMax per (query, block) -> 125 ops/address total.
    {
        int w2 = t & 7, j2 = t >> 3;
        const uint32_t* kp = keys + j2 * KPAD + w2;
        uint32_t bestv = 0;
        #pragma unroll
        for (int i = 0; i < 32; ++i) {
            uint32_t v = kp[8 * i];             // bank = (8*(j2+i)+w2)&31: 2-way max
            bestv = bestv > v ? bestv : v;
        }
        atomicMax(&best[g * 256 + w2 * 32 + j2], bestv);
    }
}

// ---------------- kernel 3: one-hot output from fused best[] -------------------
__global__ __launch_bounds__(256) void knn_out(const uint32_t* __restrict__ best,
                                               const int* __restrict__ meanings,
                                               float* __restrict__ out) {
    int q = blockIdx.x * 256 + threadIdx.x;
    if (q >= NQ) return;
    uint32_t b = best[q];
    int idx = 0x1FFFF - (int)(b & 0x1FFFFu);
    float* o = out + (size_t)q * 50;
    #pragma unroll
    for (int tt = 0; tt < 5; ++tt) {
        int mv = meanings[(size_t)idx * 5 + tt];
        #pragma unroll
        for (int mm = 0; mm < 10; ++mm) o[tt * 10 + mm] = (mm == mv) ? 1.0f : 0.0f;
    }
}

extern "C" void kernel_launch(void* const* d_in, const int* in_sizes, int n_in,
                              void* d_out, int out_size, void* d_ws, size_t ws_size,
                              hipStream_t stream) {
    const int*   utts     = (const int*)d_in[0];     // [16, 2048]
    const float* support  = (const float*)d_in[1];   // [100000, 512]
    const int*   meanings = (const int*)d_in[2];     // [100000, 5]
    float* out = (float*)d_out;                      // [2048, 5, 10]

    uint8_t*  tok  = (uint8_t*)d_ws;                                   // 1.6 MB
    uint32_t* best = (uint32_t*)((char*)d_ws + (size_t)S_ROWS * 16);   // 8 KB

    knn_decode<<<(S_ROWS + 3) / 4, 256, 0, stream>>>(support, tok, best);
    knn_score<<<GROUPS * CHUNKS, 256, 0, stream>>>(utts, tok, best);
    knn_out<<<NQ / 256, 256, 0, stream>>>(best, meanings, out);
}